// Round 1
// 480.557 us; speedup vs baseline: 2.1427x; 2.1427x over previous
//
#include <hip/hip_runtime.h>

// 2-layer tanh RNN, T=2048, B=4096, I=3, H=5. f32 storage.
//
// R6 redesign: the R5 kernel (1 thread/chain) measured 994 cyc/step vs a
// ~320-cyc issue floor -> pure dependent-latency stalls, unfixable by
// occupancy (all waves are equal-length serial chains). This version
// splits each chain over 8 lanes: lane j owns output unit j of BOTH
// layers (lanes 5..7 clamp to j=4, computing harmless duplicates), and
// the 5-wide hidden state is re-broadcast inside the 8-lane group with
// ds_swizzle after each layer. Per-step serial path: 8/10-term dot
// (dual-accumulator, ~16cy) + tanh (exp2+rcp, ~24cy) + swizzle bcast.
// Accumulation order and tanh formula are bit-identical to R5.

#define SEQ_T 2048
#define BATCH 4096
#define ISZ 3
#define HSZ 5
#define KB 8                    // x prefetch modulo-buffer depth (steps)
#define NBLK (SEQ_T / KB)

// broadcast value from lane (group_base + K) to all 8 lanes of the group
// BitMode swizzle: new_lane = (lane & 0x18) | K   (within each 32-lane half;
// groups are 8-aligned so bit 5 is preserved automatically)
template<int K>
__device__ __forceinline__ float bcastk(float v) {
    return __int_as_float(__builtin_amdgcn_ds_swizzle(__float_as_int(v), (K << 5) | 0x18));
}

// input pre-scaled by S = 2*log2(e): tanh(z) = 1 - 2*rcp(1 + exp2(S*z))
__device__ __forceinline__ float tanh_fast(float a) {
    float e = __builtin_amdgcn_exp2f(a);
    return fmaf(-2.0f, __builtin_amdgcn_rcpf(1.0f + e), 1.0f);
}

__global__ __launch_bounds__(256, 1)
void rnn2_lanes(const float* __restrict__ x, const float* __restrict__ hx,
                const float* __restrict__ w_ih0, const float* __restrict__ w_hh0,
                const float* __restrict__ b_ih0, const float* __restrict__ b_hh0,
                const float* __restrict__ w_ih1, const float* __restrict__ w_hh1,
                const float* __restrict__ b_ih1, const float* __restrict__ b_hh1,
                float* __restrict__ out)
{
    const int tid  = threadIdx.x;
    const int gthr = blockIdx.x * 256 + tid;
    const int c    = gthr >> 3;                    // chain id, 0..4095
    const int sub  = tid & 7;
    const int j    = (sub < HSZ) ? sub : (HSZ - 1); // clamped unit index
    const float S  = 2.8853900817779268f;

    // ---- per-lane weight row (VGPRs; values differ per lane) ----
    float wi0[ISZ], wh0[HSZ], wi1[HSZ], wh1[HSZ];
    const float bias0 = S * (b_ih0[j] + b_hh0[j]);
    const float bias1 = S * (b_ih1[j] + b_hh1[j]);
#pragma unroll
    for (int i = 0; i < ISZ; i++) wi0[i] = S * w_ih0[j * ISZ + i];
#pragma unroll
    for (int k = 0; k < HSZ; k++) {
        wh0[k] = S * w_hh0[j * HSZ + k];
        wi1[k] = S * w_ih1[j * HSZ + k];
        wh1[k] = S * w_hh1[j * HSZ + k];
    }

    // ---- every lane holds the full broadcast state vectors ----
    float h0b[HSZ], h1b[HSZ];
#pragma unroll
    for (int k = 0; k < HSZ; k++) {
        h0b[k] = hx[(size_t)c * HSZ + k];
        h1b[k] = hx[(size_t)BATCH * HSZ + (size_t)c * HSZ + k];
    }

    // ---- x modulo buffer: slot tt consumed, then refilled for next block ----
    const float* xp = x + (size_t)c * ISZ;
    float xbuf[KB][ISZ];
#pragma unroll
    for (int tt = 0; tt < KB; tt++)
#pragma unroll
        for (int i = 0; i < ISZ; i++)
            xbuf[tt][i] = xp[(size_t)tt * BATCH * ISZ + i];

    // lane's output column; lanes 5..7 duplicate lane 4 (same addr, same value)
    float* opv = out + (size_t)c * HSZ + j;

    for (int blk = 0; blk < NBLK; blk++) {
        // prefetch base for block+1 (clamped: last block harmlessly reloads)
        const int pf = (blk + 1 < NBLK) ? (blk + 1) * KB : blk * KB;
#pragma unroll
        for (int tt = 0; tt < KB; tt++) {
            const float xv0 = xbuf[tt][0], xv1 = xbuf[tt][1], xv2 = xbuf[tt][2];
            const float* xq = xp + (size_t)(pf + tt) * BATCH * ISZ;
            xbuf[tt][0] = xq[0]; xbuf[tt][1] = xq[1]; xbuf[tt][2] = xq[2];

            // layer 0: unit j only (accumulation order identical to R5)
            float a = bias0, cc = 0.0f;
            a  = fmaf(xv0,    wi0[0], a);
            cc = fmaf(xv1,    wi0[1], cc);
            a  = fmaf(xv2,    wi0[2], a);
            cc = fmaf(h0b[0], wh0[0], cc);
            a  = fmaf(h0b[1], wh0[1], a);
            cc = fmaf(h0b[2], wh0[2], cc);
            a  = fmaf(h0b[3], wh0[3], a);
            cc = fmaf(h0b[4], wh0[4], cc);
            a += cc;
            const float h0n = tanh_fast(a);

            // broadcast new h0 to the whole group (5 independent swizzles)
            h0b[0] = bcastk<0>(h0n);
            h0b[1] = bcastk<1>(h0n);
            h0b[2] = bcastk<2>(h0n);
            h0b[3] = bcastk<3>(h0n);
            h0b[4] = bcastk<4>(h0n);

            // layer 1: unit j (reads NEW h0b, OLD h1b — Jacobi, matches ref)
            float d = bias1, ee = 0.0f;
            d  = fmaf(h0b[0], wi1[0], d);
            ee = fmaf(h0b[1], wi1[1], ee);
            d  = fmaf(h0b[2], wi1[2], d);
            ee = fmaf(h0b[3], wi1[3], ee);
            d  = fmaf(h0b[4], wi1[4], d);
            ee = fmaf(h1b[0], wh1[0], ee);
            d  = fmaf(h1b[1], wh1[1], d);
            ee = fmaf(h1b[2], wh1[2], ee);
            d  = fmaf(h1b[3], wh1[3], d);
            ee = fmaf(h1b[4], wh1[4], ee);
            d += ee;
            const float h1n = tanh_fast(d);

            // store own unit (dup lanes race benignly with identical value)
            *opv = h1n;
            opv += (size_t)BATCH * HSZ;

            // broadcast new h1 (next use is next step's layer 1 — ample slack)
            h1b[0] = bcastk<0>(h1n);
            h1b[1] = bcastk<1>(h1n);
            h1b[2] = bcastk<2>(h1n);
            h1b[3] = bcastk<3>(h1n);
            h1b[4] = bcastk<4>(h1n);
        }
    }

    // h_n = [h0_final, h1_final], appended after out[T,B,H]
    float* hn = out + (size_t)SEQ_T * BATCH * HSZ;
    const float h0f = (j == 0) ? h0b[0] : (j == 1) ? h0b[1] :
                      (j == 2) ? h0b[2] : (j == 3) ? h0b[3] : h0b[4];
    const float h1f = (j == 0) ? h1b[0] : (j == 1) ? h1b[1] :
                      (j == 2) ? h1b[2] : (j == 3) ? h1b[3] : h1b[4];
    hn[(size_t)c * HSZ + j] = h0f;
    hn[(size_t)BATCH * HSZ + (size_t)c * HSZ + j] = h1f;
}

extern "C" void kernel_launch(void* const* d_in, const int* in_sizes, int n_in,
                              void* d_out, int out_size, void* d_ws, size_t ws_size,
                              hipStream_t stream) {
    // 4096 chains x 8 lanes = 32768 threads; 256-thread blocks -> 128 blocks,
    // 4 waves/block -> one wave per SIMD on 128 CUs.
    rnn2_lanes<<<(BATCH * 8) / 256, 256, 0, stream>>>(
        (const float*)d_in[0], (const float*)d_in[1],
        (const float*)d_in[2], (const float*)d_in[3],
        (const float*)d_in[4], (const float*)d_in[5],
        (const float*)d_in[6], (const float*)d_in[7],
        (const float*)d_in[8], (const float*)d_in[9],
        (float*)d_out);
}